// Round 2
// baseline (209.120 us; speedup 1.0000x reference)
//
#include <hip/hip_runtime.h>

#define B_ 64
#define N_ 64
#define D_ 256
#define LAP_ 16
#define M_ 2016           // 64*63/2
#define TOK_ 2081         // 1 + 64 + 2016

typedef float v4f __attribute__((ext_vector_type(4)));
typedef float v2f __attribute__((ext_vector_type(2)));

// Map linear upper-tri index m -> (i, j), i<j, row-major over triu(k=1).
// off(i) = (127*i - i*i)/2
__device__ __forceinline__ void ij_from_m(int m, int& i, int& j) {
    float fm = (float)m;
    int gi = (int)((127.0f - sqrtf(127.0f * 127.0f - 8.0f * fm)) * 0.5f);
    if (gi < 0) gi = 0;
    if (gi > 62) gi = 62;
    while (gi > 0 && (127 * gi - gi * gi) / 2 > m) gi--;
    while (gi < 62 && (127 * (gi + 1) - (gi + 1) * (gi + 1)) / 2 <= m) gi++;
    i = gi;
    j = gi + 1 + (m - (127 * gi - gi * gi) / 2);
}

// ---------------------------------------------------------------------------
// One fused kernel. Grid (B, 64), 256 threads.
//   y in [0,63): edge block, output tokens p in [y*32, y*32+32).
//     - recompute batch-b compaction locally: ballot -> 32 u64 words in LDS,
//       popcount prefix scan, then rank/select for this block's 32 slots.
//     - lane owns 2 output columns (float2 weights: 66 VGPR resident) so the
//       whole kernel fits <=128 VGPR -> 4 waves/SIMD.
//   y == 63: node tokens + graph token + head of pad_mask (VALU-balanced
//     with edge blocks: 1024 fmac/lane each).
// ---------------------------------------------------------------------------
__global__ __launch_bounds__(256, 4) void fused_kernel(
    const int*   __restrict__ adj,
    const float* __restrict__ node_feats,
    const float* __restrict__ eigvec,
    const float* __restrict__ W_lap,
    const float* __restrict__ W_edge,
    const float* __restrict__ b_edge,
    const float* __restrict__ type_embed,
    const float* __restrict__ graph_tok,
    float*       __restrict__ out)
{
    __shared__ float sEig[N_ * LAP_];          // 4 KB: this batch's eigvec
    __shared__ unsigned long long sWords[32];  // 2016-bit valid mask
    __shared__ int sPref[32];                  // exclusive popcount prefix
    __shared__ int sTok[32];                   // i | j<<8 | valid<<16 per slot
    __shared__ int sTotal;

    const int b = blockIdx.x;
    const int y = blockIdx.y;
    const int t = threadIdx.x;
    const int wave = t >> 6, lane = t & 63;

    ((float4*)sEig)[t] = ((const float4*)(eigvec + (size_t)b * N_ * LAP_))[t];

    if (y == 63) {
        // ---- node tokens + graph token + mask head ----
        float4 wl[LAP_];
#pragma unroll
        for (int l = 0; l < LAP_; l++)
            wl[l] = ((const float4*)(W_lap + l * D_))[lane];
        __syncthreads();
        float* outB = out + (size_t)b * TOK_ * D_;
#pragma unroll 2
        for (int it = 0; it < 16; it++) {
            int n = it * 4 + wave;
            float4 a = ((const float4*)(node_feats + ((size_t)b * N_ + n) * D_))[lane];
            const float* e = sEig + n * LAP_;
#pragma unroll
            for (int l = 0; l < LAP_; l++) {
                float el = e[l];
                a.x += el * wl[l].x; a.y += el * wl[l].y;
                a.z += el * wl[l].z; a.w += el * wl[l].w;
            }
            __builtin_nontemporal_store(*(const v4f*)&a,
                (v4f*)(outB + (size_t)(1 + n) * D_) + lane);
        }
        outB[t] = graph_tok[t];                        // graph token (256 floats)
        if (t < 1 + N_)
            out[(size_t)B_ * TOK_ * D_ + (size_t)b * TOK_ + t] = 0.0f;
        return;
    }

    // ---- edge block ----
    // Phase A: valid bitmask via ballot. Thread t covers m = k*256 + t.
#pragma unroll
    for (int k = 0; k < 8; k++) {
        int m = k * 256 + t;
        int valid = 0;
        if (m < M_) {
            int i, j;
            ij_from_m(m, i, j);
            valid = (adj[b * (N_ * N_) + i * N_ + j] > 0) ? 1 : 0;
        }
        unsigned long long blt = __ballot(valid);
        if (lane == 0) sWords[k * 4 + wave] = blt;     // word w holds m in [w*64, w*64+64)
    }

    // Register-resident weights for this lane's 2 columns (issued early,
    // consumed after the barrier -> latency hidden under phases A-C).
    const int h = wave & 1;            // column half: [0,128) or [128,256)
    const int cbase = h * 128 + lane * 2;
    float2 base2;
    base2.x = W_edge[cbase]     + b_edge[cbase]     + type_embed[D_ + cbase];
    base2.y = W_edge[cbase + 1] + b_edge[cbase + 1] + type_embed[D_ + cbase + 1];
    float2 w1[LAP_], w2[LAP_];
#pragma unroll
    for (int l = 0; l < LAP_; l++) {
        w1[l] = *(const float2*)(W_edge + (1 + l) * D_ + cbase);
        w2[l] = *(const float2*)(W_edge + (1 + LAP_ + l) * D_ + cbase);
    }
    __syncthreads();

    // Phase B: popcount prefix over the 32 words (wave 0, lanes 0..31).
    if (t < 32) {
        int c = __popcll(sWords[t]);
        int inc = c;
#pragma unroll
        for (int off = 1; off < 32; off <<= 1) {
            int v = __shfl_up(inc, off);
            if (lane >= off) inc += v;
        }
        sPref[t] = inc - c;
        if (t == 31) sTotal = inc;
    }
    __syncthreads();

    // Phase C: rank/select for this block's 32 output slots + mask writes.
    const int total = sTotal;
    if (t < 32) {
        int p = y * 32 + t;
        int m, valid;
        if (p < total) {                     // p-th valid edge (stable order)
            valid = 1;
            int r = p;
            int w = 0;
            while (w < 31 && sPref[w + 1] <= r) w++;
            unsigned long long x = sWords[w];
            int rr = r - sPref[w];
            for (int q = 0; q < rr; q++) x &= x - 1;
            m = w * 64 + __builtin_ctzll(x);
        } else {                             // (p-total)-th invalid edge
            valid = 0;
            int r = p - total;
            int w = 0;
            while (w < 31 && (w + 1) * 64 - sPref[w + 1] <= r) w++;
            unsigned long long x = ~sWords[w];
            if (w == 31) x &= 0xFFFFFFFFull; // only 32 real edges in last word
            int rr = r - (w * 64 - sPref[w]);
            for (int q = 0; q < rr; q++) x &= x - 1;
            m = w * 64 + __builtin_ctzll(x);
        }
        int i, j;
        ij_from_m(m, i, j);
        sTok[t] = i | (j << 8) | (valid << 16);
        out[(size_t)B_ * TOK_ * D_ + (size_t)b * TOK_ + 1 + N_ + p] =
            valid ? 0.0f : 1.0f;
    }
    __syncthreads();

    // Phase D: compute + store. Wave pair (tg) covers 16 tokens; lane owns
    // 2 columns. Per token: 8 uniform ds_read_b128 + 64 fmac + store_dwordx2.
    float* outE = out + (size_t)b * TOK_ * D_ + (size_t)(1 + N_) * D_;
    const int tg = wave >> 1;
#pragma unroll 2
    for (int tt = 0; tt < 16; tt++) {
        int slot = tg * 16 + tt;
        int info = sTok[slot];
        int p = y * 32 + slot;
        float2 acc = make_float2(0.0f, 0.0f);
        if (info >> 16) {
            int si = info & 0xff, di = (info >> 8) & 0xff;
            const float4* eu4 = (const float4*)(sEig + si * LAP_);
            const float4* ev4 = (const float4*)(sEig + di * LAP_);
            acc = base2;
#pragma unroll
            for (int q = 0; q < 4; q++) {
                float4 u = eu4[q];
                float4 v = ev4[q];
                acc.x += u.x * w1[q*4+0].x + v.x * w2[q*4+0].x;
                acc.y += u.x * w1[q*4+0].y + v.x * w2[q*4+0].y;
                acc.x += u.y * w1[q*4+1].x + v.y * w2[q*4+1].x;
                acc.y += u.y * w1[q*4+1].y + v.y * w2[q*4+1].y;
                acc.x += u.z * w1[q*4+2].x + v.z * w2[q*4+2].x;
                acc.y += u.z * w1[q*4+2].y + v.z * w2[q*4+2].y;
                acc.x += u.w * w1[q*4+3].x + v.w * w2[q*4+3].x;
                acc.y += u.w * w1[q*4+3].y + v.w * w2[q*4+3].y;
            }
        }
        __builtin_nontemporal_store(*(const v2f*)&acc,
            (v2f*)(outE + (size_t)p * D_ + cbase));
    }
}

extern "C" void kernel_launch(void* const* d_in, const int* in_sizes, int n_in,
                              void* d_out, int out_size, void* d_ws, size_t ws_size,
                              hipStream_t stream) {
    const int*   adj        = (const int*)d_in[0];
    const float* node_feats = (const float*)d_in[1];
    const float* eigvec     = (const float*)d_in[2];
    const float* W_lap      = (const float*)d_in[3];
    const float* W_edge     = (const float*)d_in[4];
    const float* b_edge     = (const float*)d_in[5];
    const float* type_embed = (const float*)d_in[6];
    const float* graph_tok  = (const float*)d_in[7];
    float* out = (float*)d_out;

    fused_kernel<<<dim3(B_, 64), dim3(256), 0, stream>>>(
        adj, node_feats, eigvec, W_lap, W_edge, b_edge, type_embed, graph_tok, out);
}

// Round 3
// 193.850 us; speedup vs baseline: 1.0788x; 1.0788x over previous
//
#include <hip/hip_runtime.h>

#define B_ 64
#define N_ 64
#define D_ 256
#define LAP_ 16
#define M_ 2016           // 64*63/2
#define TOK_ 2081         // 1 + 64 + 2016

typedef float v4f __attribute__((ext_vector_type(4)));

// Map linear upper-tri index m -> (i, j), i<j, row-major over triu(k=1).
// off(i) = (127*i - i*i)/2
__device__ __forceinline__ void ij_from_m(int m, int& i, int& j) {
    float fm = (float)m;
    int gi = (int)((127.0f - sqrtf(127.0f * 127.0f - 8.0f * fm)) * 0.5f);
    if (gi < 0) gi = 0;
    if (gi > 62) gi = 62;
    while (gi > 0 && (127 * gi - gi * gi) / 2 > m) gi--;
    while (gi < 62 && (127 * (gi + 1) - (gi + 1) * (gi + 1)) / 2 <= m) gi++;
    i = gi;
    j = gi + 1 + (m - (127 * gi - gi * gi) / 2);
}

// ---------------------------------------------------------------------------
// One fused kernel. Grid (B, 64), 256 threads. Lane owns ONE output column
// (c = threadIdx.x) -> resident weights are 33 scalars, ~90 VGPR total, so
// the compiler keeps them in registers (last round's 128-cap squeeze made it
// rematerialize 33 float2 loads per token -> VALU-bound at 64 VGPR).
//   y in [0,63): edge block for tokens m in [y*32, y*32+32).
//     SCATTER form: full valid bitmask (ballot -> 32 u64 in LDS) + shfl
//     prefix scan gives each m its destination slot in closed form:
//       p = valid ? rank(m) : total + (m - rank(m))
//     No serial select loops (last round's latency-bound Phase C).
//   y == 63: node tokens + graph token + mask head.
// ---------------------------------------------------------------------------
__global__ __launch_bounds__(256, 2) void fused_kernel(
    const int*   __restrict__ adj,
    const float* __restrict__ node_feats,
    const float* __restrict__ eigvec,
    const float* __restrict__ W_lap,
    const float* __restrict__ W_edge,
    const float* __restrict__ b_edge,
    const float* __restrict__ type_embed,
    const float* __restrict__ graph_tok,
    float*       __restrict__ out)
{
    __shared__ float sEig[N_ * LAP_];          // 4 KB: this batch's eigvec
    __shared__ unsigned long long sWords[32];  // 2016-bit valid mask
    __shared__ int sTok[32];                   // i | j<<6 | valid<<12 | p<<13

    const int b = blockIdx.x;
    const int y = blockIdx.y;
    const int t = threadIdx.x;
    const int wave = t >> 6, lane = t & 63;
    const int c = t;                           // this lane's output column

    ((float4*)sEig)[t] = ((const float4*)(eigvec + (size_t)b * N_ * LAP_))[t];

    if (y == 63) {
        // ---- node tokens + graph token + mask head ----
        float wl[LAP_];
#pragma unroll
        for (int l = 0; l < LAP_; l++) wl[l] = W_lap[l * D_ + c];
        __syncthreads();
        float* outB = out + (size_t)b * TOK_ * D_;
#pragma unroll 4
        for (int n = 0; n < N_; n++) {
            float a = node_feats[((size_t)b * N_ + n) * D_ + c];
            const float* e = sEig + n * LAP_;
#pragma unroll
            for (int l = 0; l < LAP_; l++) a += e[l] * wl[l];
            __builtin_nontemporal_store(a, outB + (size_t)(1 + n) * D_ + c);
        }
        outB[t] = graph_tok[t];                // graph token (256 floats)
        if (t < 1 + N_)
            out[(size_t)B_ * TOK_ * D_ + (size_t)b * TOK_ + t] = 0.0f;
        return;
    }

    // ---- edge block ----
    // Phase A: full valid bitmask via ballot. Thread t covers m = k*256 + t.
#pragma unroll
    for (int k = 0; k < 8; k++) {
        int m = k * 256 + t;
        int valid = 0;
        if (m < M_) {
            int i, j;
            ij_from_m(m, i, j);
            valid = (adj[b * (N_ * N_) + i * N_ + j] > 0) ? 1 : 0;
        }
        unsigned long long blt = __ballot(valid);
        if (lane == 0) sWords[k * 4 + wave] = blt;   // word w holds m in [w*64, (w+1)*64)
    }

    // Resident weights for this lane's single column (33 scalars).
    float base = W_edge[c] + b_edge[c] + type_embed[D_ + c];
    float w1[LAP_], w2[LAP_];
#pragma unroll
    for (int l = 0; l < LAP_; l++) {
        w1[l] = W_edge[(1 + l) * D_ + c];
        w2[l] = W_edge[(1 + LAP_ + l) * D_ + c];
    }
    __syncthreads();   // sWords + sEig ready

    // Phase B: rank + destination slot for this block's 32 edges (t < 32).
    if (t < 32) {
        unsigned long long word = sWords[t];
        int cnt = __popcll(word);
        int inc = cnt;
#pragma unroll
        for (int off = 1; off < 32; off <<= 1) {
            int v = __shfl_up(inc, off);
            if (lane >= off) inc += v;
        }
        int pref  = inc - cnt;                 // exclusive prefix of word t
        int total = __shfl(inc, 31);           // total valid edges
        int m = y * 32 + t;
        int w = m >> 6, r = m & 63;
        unsigned long long ww = __shfl(word, w);
        int pw = __shfl(pref, w);
        int rank = pw + __popcll(ww & ((1ull << r) - 1ull));
        int valid = (int)((ww >> r) & 1ull);
        int p = valid ? rank : total + (m - rank);
        int i, j;
        ij_from_m(m, i, j);
        sTok[t] = i | (j << 6) | (valid << 12) | (p << 13);
        out[(size_t)B_ * TOK_ * D_ + (size_t)b * TOK_ + 1 + N_ + p] =
            valid ? 0.0f : 1.0f;
    }
    __syncthreads();

    // Phase C: compute + scatter-store. All 4 waves iterate all 32 tokens;
    // each wave stores its 64-column slice (256 B contiguous per store).
    float* outE = out + (size_t)b * TOK_ * D_ + (size_t)(1 + N_) * D_;
#pragma unroll 2
    for (int k = 0; k < 32; k++) {
        int info = sTok[k];                    // wave-uniform broadcast
        int p = info >> 13;
        float acc = 0.0f;
        if (info & (1 << 12)) {
            int si = info & 63, di = (info >> 6) & 63;
            const v4f* eu4 = (const v4f*)(sEig + si * LAP_);
            const v4f* ev4 = (const v4f*)(sEig + di * LAP_);
            acc = base;
#pragma unroll
            for (int q = 0; q < 4; q++) {
                v4f u = eu4[q];
                v4f v = ev4[q];
                acc += u.x * w1[q * 4 + 0] + v.x * w2[q * 4 + 0];
                acc += u.y * w1[q * 4 + 1] + v.y * w2[q * 4 + 1];
                acc += u.z * w1[q * 4 + 2] + v.z * w2[q * 4 + 2];
                acc += u.w * w1[q * 4 + 3] + v.w * w2[q * 4 + 3];
            }
        }
        __builtin_nontemporal_store(acc, outE + (size_t)p * D_ + c);
    }
}

extern "C" void kernel_launch(void* const* d_in, const int* in_sizes, int n_in,
                              void* d_out, int out_size, void* d_ws, size_t ws_size,
                              hipStream_t stream) {
    const int*   adj        = (const int*)d_in[0];
    const float* node_feats = (const float*)d_in[1];
    const float* eigvec     = (const float*)d_in[2];
    const float* W_lap      = (const float*)d_in[3];
    const float* W_edge     = (const float*)d_in[4];
    const float* b_edge     = (const float*)d_in[5];
    const float* type_embed = (const float*)d_in[6];
    const float* graph_tok  = (const float*)d_in[7];
    float* out = (float*)d_out;

    fused_kernel<<<dim3(B_, 64), dim3(256), 0, stream>>>(
        adj, node_feats, eigvec, W_lap, W_edge, b_edge, type_embed, graph_tok, out);
}

// Round 4
// 187.377 us; speedup vs baseline: 1.1160x; 1.0345x over previous
//
#include <hip/hip_runtime.h>

#define B_ 64
#define N_ 64
#define D_ 256
#define LAP_ 16
#define M_ 2016           // 64*63/2
#define TOK_ 2081         // 1 + 64 + 2016

// Map linear upper-tri index m -> (i, j), i<j, row-major over triu(k=1).
// off(i) = (127*i - i*i)/2
__device__ __forceinline__ void ij_from_m(int m, int& i, int& j) {
    float fm = (float)m;
    int gi = (int)((127.0f - sqrtf(127.0f * 127.0f - 8.0f * fm)) * 0.5f);
    if (gi < 0) gi = 0;
    if (gi > 62) gi = 62;
    while (gi > 0 && (127 * gi - gi * gi) / 2 > m) gi--;
    while (gi < 62 && (127 * (gi + 1) - (gi + 1) * (gi + 1)) / 2 <= m) gi++;
    i = gi;
    j = gi + 1 + (m - (127 * gi - gi * gi) / 2);
}

// ---------------------------------------------------------------------------
// Separable edge tokens: etok[u,v] = base + (Pu.W1) + (Pv.W2).
// Precompute U = eigvec.W1, V = eigvec.W2 per (batch, 64-column slice) in LDS,
// then each edge token is 2 adds/column (was 32 FMAs/column -> ~30x FLOPs cut).
// Grid (B, 4): block (b, cg) owns columns [cg*64, cg*64+64); 4 waves split the
// row/token dimension. One block per CU; kernel should be output-write-bound.
// ---------------------------------------------------------------------------
__global__ __launch_bounds__(256, 2) void fused_kernel(
    const int*   __restrict__ adj,
    const float* __restrict__ node_feats,
    const float* __restrict__ eigvec,
    const float* __restrict__ W_lap,
    const float* __restrict__ W_edge,
    const float* __restrict__ b_edge,
    const float* __restrict__ type_embed,
    const float* __restrict__ graph_tok,
    float*       __restrict__ out)
{
    __shared__ float sEig[N_ * LAP_];          // 4 KB
    __shared__ float sU[N_ * 64];              // 16 KB: (eigvec.W1)[n, colslice]
    __shared__ float sV[N_ * 64];              // 16 KB: (eigvec.W2)[n, colslice]
    __shared__ int   sDest[M_];                // 8 KB: i | j<<6 | valid<<12 | p<<13
    __shared__ unsigned long long sWords[32];  // 2016-bit valid mask
    __shared__ int sPref[32];
    __shared__ int sTotal;

    const int b    = blockIdx.x;
    const int cg   = blockIdx.y;               // column group
    const int t    = threadIdx.x;
    const int wave = t >> 6, lane = t & 63;
    const int c    = cg * 64 + lane;           // this lane's output column

    // ---- stage eigvec, issue adj loads, load weights ----
    ((float4*)sEig)[t] = ((const float4*)(eigvec + (size_t)b * N_ * LAP_))[t];

    int ival[8];                               // i | j<<6 (then |valid<<12)
    int av[8];
#pragma unroll
    for (int k = 0; k < 8; k++) {
        int m = k * 256 + t;
        int i = 0, j = 0;
        if (m < M_) {
            ij_from_m(m, i, j);
            av[k] = adj[b * (N_ * N_) + i * N_ + j];
        } else av[k] = 0;
        ival[k] = i | (j << 6);
    }

    float base = W_edge[c] + b_edge[c] + type_embed[D_ + c];
    float w1c[LAP_], w2c[LAP_], wlc[LAP_];
#pragma unroll
    for (int l = 0; l < LAP_; l++) {
        w1c[l] = W_edge[(1 + l) * D_ + c];
        w2c[l] = W_edge[(1 + LAP_ + l) * D_ + c];
        wlc[l] = W_lap[l * D_ + c];
    }

    // ---- ballot -> bitmask words ----
#pragma unroll
    for (int k = 0; k < 8; k++) {
        int valid = (k * 256 + t < M_) && (av[k] > 0);
        unsigned long long blt = __ballot(valid);
        if (lane == 0) sWords[k * 4 + wave] = blt;  // word w covers m in [w*64,(w+1)*64)
        ival[k] |= valid << 12;
    }
    __syncthreads();   // sEig + sWords ready

    // ---- popcount prefix scan (wave 0, lanes 0..31) ----
    if (t < 32) {
        unsigned long long word = sWords[t];
        int cnt = __popcll(word);
        int inc = cnt;
#pragma unroll
        for (int off = 1; off < 32; off <<= 1) {
            int v = __shfl_up(inc, off);
            if (lane >= off) inc += v;
        }
        sPref[t] = inc - cnt;
        if (t == 31) sTotal = inc;
    }

    // ---- U, V partials for this column slice (waves split nodes) ----
#pragma unroll 2
    for (int n16 = 0; n16 < 16; n16++) {
        int n = wave * 16 + n16;
        const float* e = sEig + n * LAP_;
        float accU = 0.0f, accV = 0.0f;
#pragma unroll
        for (int l = 0; l < LAP_; l++) {
            float el = e[l];
            accU += el * w1c[l];
            accV += el * w2c[l];
        }
        sU[n * 64 + lane] = accU;
        sV[n * 64 + lane] = accV;
    }
    __syncthreads();   // sPref/sTotal + sU/sV ready

    // ---- destination slots (scatter rank) + edge mask ----
    const int total = sTotal;
    float* maskb = out + (size_t)B_ * TOK_ * D_ + (size_t)b * TOK_;
#pragma unroll
    for (int k = 0; k < 8; k++) {
        int m = k * 256 + t;
        if (m < M_) {
            int w = k * 4 + wave;              // wave-uniform -> LDS broadcast
            unsigned long long word = sWords[w];
            int rank = sPref[w] + __popcll(word & ((1ull << lane) - 1ull));
            int valid = (ival[k] >> 12) & 1;
            int p = valid ? rank : total + (m - rank);
            sDest[m] = (ival[k] & 0xFFF) | (valid << 12) | (p << 13);
            if (cg == 0) maskb[1 + N_ + p] = valid ? 0.0f : 1.0f;
        }
    }

    // ---- node tokens + graph token + mask head (needs only sEig + wlc) ----
    float* outB = out + (size_t)b * TOK_ * D_;
#pragma unroll 2
    for (int n16 = 0; n16 < 16; n16++) {
        int n = wave * 16 + n16;
        float a = node_feats[((size_t)b * N_ + n) * D_ + c];
        const float* e = sEig + n * LAP_;
#pragma unroll
        for (int l = 0; l < LAP_; l++) a += e[l] * wlc[l];
        __builtin_nontemporal_store(a, outB + (size_t)(1 + n) * D_ + c);
    }
    if (wave == 0) outB[c] = graph_tok[c];
    if (cg == 0 && t < 1 + N_) maskb[t] = 0.0f;
    __syncthreads();   // sDest ready

    // ---- edge tokens: 2 adds per column, contiguous 256 B store per wave ----
    float* outE = outB + (size_t)(1 + N_) * D_;
#pragma unroll 4
    for (int q = 0; q < M_ / 4; q++) {
        int m = wave * (M_ / 4) + q;
        int info = sDest[m];                   // wave-uniform broadcast
        int p = info >> 13;
        float val = 0.0f;
        if (info & (1 << 12)) {                // wave-uniform branch
            int si = info & 63, di = (info >> 6) & 63;
            val = base + sU[si * 64 + lane] + sV[di * 64 + lane];
        }
        __builtin_nontemporal_store(val, outE + (size_t)p * D_ + c);
    }
}

extern "C" void kernel_launch(void* const* d_in, const int* in_sizes, int n_in,
                              void* d_out, int out_size, void* d_ws, size_t ws_size,
                              hipStream_t stream) {
    const int*   adj        = (const int*)d_in[0];
    const float* node_feats = (const float*)d_in[1];
    const float* eigvec     = (const float*)d_in[2];
    const float* W_lap      = (const float*)d_in[3];
    const float* W_edge     = (const float*)d_in[4];
    const float* b_edge     = (const float*)d_in[5];
    const float* type_embed = (const float*)d_in[6];
    const float* graph_tok  = (const float*)d_in[7];
    float* out = (float*)d_out;

    fused_kernel<<<dim3(B_, 4), dim3(256), 0, stream>>>(
        adj, node_feats, eigvec, W_lap, W_edge, b_edge, type_embed, graph_tok, out);
}

// Round 5
// 179.473 us; speedup vs baseline: 1.1652x; 1.0440x over previous
//
#include <hip/hip_runtime.h>

#define B_ 64
#define N_ 64
#define D_ 256
#define LAP_ 16
#define M_ 2016           // 64*63/2
#define TOK_ 2081         // 1 + 64 + 2016
#define MPB_ 504          // edges per block (M_/4)
#define MPW_ 126          // edges per wave (MPB_/4)

typedef float v4f __attribute__((ext_vector_type(4)));

// Map linear upper-tri index m -> (i, j), i<j, row-major over triu(k=1).
// off(i) = (127*i - i*i)/2
__device__ __forceinline__ void ij_from_m(int m, int& i, int& j) {
    float fm = (float)m;
    int gi = (int)((127.0f - sqrtf(127.0f * 127.0f - 8.0f * fm)) * 0.5f);
    if (gi < 0) gi = 0;
    if (gi > 62) gi = 62;
    while (gi > 0 && (127 * gi - gi * gi) / 2 > m) gi--;
    while (gi < 62 && (127 * (gi + 1) - (gi + 1) * (gi + 1)) / 2 <= m) gi++;
    i = gi;
    j = gi + 1 + (m - (127 * gi - gi * gi) / 2);
}

// ---------------------------------------------------------------------------
// Separable edge tokens, full-width blocks:
//   etok[u,v,:] = base[:] + U[u,:] + V[v,:],  U = eig.W1, V = eig.W2.
// Grid (B, 4): block (b, cg) stages FULL-width U,V (64 KB each) in LDS and
// owns source edges m in [cg*504, cg*504+504); each wave emits one whole
// 1 KB token row per iteration (float4/lane): 2 conflict-free ds_read_b128 +
// 1 global_store_dwordx4. Write-drain-bound by design (~10 B/cyc/CU).
// Last round's failure: 4 B/lane stores + 1 wave/SIMD latency wall.
// ---------------------------------------------------------------------------
__global__ __launch_bounds__(256, 1) void fused_kernel(
    const int*   __restrict__ adj,
    const float* __restrict__ node_feats,
    const float* __restrict__ eigvec,
    const float* __restrict__ W_lap,
    const float* __restrict__ W_edge,
    const float* __restrict__ b_edge,
    const float* __restrict__ type_embed,
    const float* __restrict__ graph_tok,
    float*       __restrict__ out)
{
    __shared__ float sEig[N_ * LAP_];          // 4 KB
    __shared__ float sU[N_ * D_];              // 64 KB: (eig.W1)[n, 0..256)
    __shared__ float sV[N_ * D_];              // 64 KB: (eig.W2)[n, 0..256)
    __shared__ unsigned long long sWords[32];  // 2016-bit valid mask
    __shared__ int sPref[32];
    __shared__ int sDest[MPB_];                // i | j<<6 | valid<<12 | p<<13
    __shared__ int sTotal;

    const int b    = blockIdx.x;
    const int cg   = blockIdx.y;               // source-edge group
    const int t    = threadIdx.x;
    const int wave = t >> 6, lane = t & 63;

    // ---- stage eigvec + full valid bitmask via ballot ----
    ((float4*)sEig)[t] = ((const float4*)(eigvec + (size_t)b * N_ * LAP_))[t];
#pragma unroll
    for (int k = 0; k < 8; k++) {
        int m = k * 256 + t;
        int valid = 0;
        if (m < M_) {
            int i, j;
            ij_from_m(m, i, j);
            valid = (adj[b * (N_ * N_) + i * N_ + j] > 0) ? 1 : 0;
        }
        unsigned long long blt = __ballot(valid);
        if (lane == 0) sWords[k * 4 + wave] = blt;  // word w covers [w*64,(w+1)*64)
    }

    // per-thread column weights (column c = t) for U/V/node partials
    float w1c[LAP_], w2c[LAP_], wlc[LAP_];
#pragma unroll
    for (int l = 0; l < LAP_; l++) {
        w1c[l] = W_edge[(1 + l) * D_ + t];
        w2c[l] = W_edge[(1 + LAP_ + l) * D_ + t];
        wlc[l] = W_lap[l * D_ + t];
    }
    // per-lane float4 base for the edge loop (columns 4*lane..4*lane+3)
    v4f base4 = *((const v4f*)W_edge + lane);
    base4 += *((const v4f*)b_edge + lane);
    base4 += *((const v4f*)(type_embed + D_) + lane);

    __syncthreads();   // sEig + sWords ready

    // ---- popcount prefix scan (wave 0, lanes 0..31) ----
    if (t < 32) {
        int cnt = __popcll(sWords[t]);
        int inc = cnt;
#pragma unroll
        for (int off = 1; off < 32; off <<= 1) {
            int v = __shfl_up(inc, off);
            if (lane >= off) inc += v;
        }
        sPref[t] = inc - cnt;
        if (t == 31) sTotal = inc;
    }

    // ---- full-width U,V partials: thread owns column t, all 64 nodes ----
#pragma unroll 4
    for (int n = 0; n < N_; n++) {
        const v4f* e4 = (const v4f*)(sEig + n * LAP_);   // wave-uniform: broadcast
        v4f e0 = e4[0], e1 = e4[1], e2 = e4[2], e3 = e4[3];
        float aU, aV;
        aU  = e0.x * w1c[0]  + e0.y * w1c[1]  + e0.z * w1c[2]  + e0.w * w1c[3];
        aU += e1.x * w1c[4]  + e1.y * w1c[5]  + e1.z * w1c[6]  + e1.w * w1c[7];
        aU += e2.x * w1c[8]  + e2.y * w1c[9]  + e2.z * w1c[10] + e2.w * w1c[11];
        aU += e3.x * w1c[12] + e3.y * w1c[13] + e3.z * w1c[14] + e3.w * w1c[15];
        aV  = e0.x * w2c[0]  + e0.y * w2c[1]  + e0.z * w2c[2]  + e0.w * w2c[3];
        aV += e1.x * w2c[4]  + e1.y * w2c[5]  + e1.z * w2c[6]  + e1.w * w2c[7];
        aV += e2.x * w2c[8]  + e2.y * w2c[9]  + e2.z * w2c[10] + e2.w * w2c[11];
        aV += e3.x * w2c[12] + e3.y * w2c[13] + e3.z * w2c[14] + e3.w * w2c[15];
        sU[n * D_ + t] = aU;
        sV[n * D_ + t] = aV;
    }
    __syncthreads();   // sPref/sTotal + sU/sV ready

    // ---- destination slots for this block's 504 source edges + edge mask ----
    const int total = sTotal;
    float* maskb = out + (size_t)B_ * TOK_ * D_ + (size_t)b * TOK_;
    for (int idx = t; idx < MPB_; idx += 256) {
        int m = cg * MPB_ + idx;
        int w = m >> 6, r = m & 63;
        unsigned long long word = sWords[w];
        int rank = sPref[w] + __popcll(word & ((1ull << r) - 1ull));
        int valid = (int)((word >> r) & 1ull);
        int p = valid ? rank : total + (m - rank);
        int i, j;
        ij_from_m(m, i, j);
        sDest[idx] = i | (j << 6) | (valid << 12) | (p << 13);
        maskb[1 + N_ + p] = valid ? 0.0f : 1.0f;
    }

    // ---- node tokens (block cg owns nodes cg*16..cg*16+16) + extras ----
    float* outB = out + (size_t)b * TOK_ * D_;
#pragma unroll 4
    for (int k = 0; k < 16; k++) {
        int n = cg * 16 + k;
        float a = node_feats[((size_t)b * N_ + n) * D_ + t];
        const float* e = sEig + n * LAP_;
#pragma unroll
        for (int l = 0; l < LAP_; l++) a += e[l] * wlc[l];
        __builtin_nontemporal_store(a, outB + (size_t)(1 + n) * D_ + t);
    }
    if (cg == 0) {
        outB[t] = graph_tok[t];                // graph token
        if (t < 1 + N_) maskb[t] = 0.0f;       // mask head
    }
    __syncthreads();   // sDest ready

    // ---- edge tokens: one whole 1 KB row per wave-iteration ----
    float* outE = outB + (size_t)(1 + N_) * D_;
#pragma unroll 2
    for (int q = 0; q < MPW_; q++) {
        int info = sDest[wave * MPW_ + q];     // wave-uniform broadcast
        int p = info >> 13;
        v4f val = {0.0f, 0.0f, 0.0f, 0.0f};
        if (info & (1 << 12)) {                // wave-uniform branch
            int si = info & 63, di = (info >> 6) & 63;
            v4f u = ((const v4f*)(sU + si * D_))[lane];
            v4f v = ((const v4f*)(sV + di * D_))[lane];
            val = base4 + u + v;
        }
        __builtin_nontemporal_store(val, (v4f*)(outE + (size_t)p * D_) + lane);
    }
}

extern "C" void kernel_launch(void* const* d_in, const int* in_sizes, int n_in,
                              void* d_out, int out_size, void* d_ws, size_t ws_size,
                              hipStream_t stream) {
    const int*   adj        = (const int*)d_in[0];
    const float* node_feats = (const float*)d_in[1];
    const float* eigvec     = (const float*)d_in[2];
    const float* W_lap      = (const float*)d_in[3];
    const float* W_edge     = (const float*)d_in[4];
    const float* b_edge     = (const float*)d_in[5];
    const float* type_embed = (const float*)d_in[6];
    const float* graph_tok  = (const float*)d_in[7];
    float* out = (float*)d_out;

    fused_kernel<<<dim3(B_, 4), dim3(256), 0, stream>>>(
        adj, node_feats, eigvec, W_lap, W_edge, b_edge, type_embed, graph_tok, out);
}